// Round 2
// baseline (18330.214 us; speedup 1.0000x reference)
//
#include <hip/hip_runtime.h>
#include <hip/hip_bf16.h>
#include <stdint.h>

#define BS 512
#define D 1024
#define H 4096
#define T_STEPS 64
#define N_INNER 4

typedef __attribute__((ext_vector_type(8))) short bf16x8;
typedef __attribute__((ext_vector_type(4))) float f32x4;
typedef unsigned short u16;

__device__ __forceinline__ u16 f2bf(float f) {
    unsigned int u = __float_as_uint(f);
    unsigned int r = (u + 0x7FFFu + ((u >> 16) & 1u)) >> 16;
    return (u16)r;
}
__device__ __forceinline__ float bf2f(u16 h) {
    return __uint_as_float(((unsigned int)h) << 16);
}

// ---------------- prep kernels ----------------

// src [rows][cols] f32 -> dst_hi/dst_lo [cols][rows] bf16 (hi+lo split)
__global__ __launch_bounds__(256) void transpose_split(
    const float* __restrict__ src, u16* __restrict__ dst_hi,
    u16* __restrict__ dst_lo, int rows, int cols) {
    __shared__ float tile[32][33];
    const int bx = blockIdx.x;            // col tile
    const int by = blockIdx.y;            // row tile
    const int tx = threadIdx.x & 31;
    const int ty = threadIdx.x >> 5;      // 0..7
    const int c0 = bx * 32, r0 = by * 32;
    #pragma unroll
    for (int i = ty; i < 32; i += 8)
        tile[i][tx] = src[(size_t)(r0 + i) * cols + c0 + tx];
    __syncthreads();
    #pragma unroll
    for (int i = ty; i < 32; i += 8) {
        const float v = tile[tx][i];
        const u16 hi = f2bf(v);
        const u16 lo = f2bf(v - bf2f(hi));
        const size_t idx = (size_t)(c0 + i) * rows + r0 + tx;
        dst_hi[idx] = hi;
        dst_lo[idx] = lo;
    }
}

__global__ __launch_bounds__(256) void init_z(
    const float* __restrict__ z0, float* __restrict__ z_cur,
    u16* __restrict__ z_hi, u16* __restrict__ z_lo, float* __restrict__ out) {
    const int i = blockIdx.x * 256 + threadIdx.x;
    const float v = z0[i];
    z_cur[i] = v;
    const u16 hi = f2bf(v);
    z_hi[i] = hi;
    z_lo[i] = f2bf(v - bf2f(hi));
    out[i] = v;
}

// ---------------- fused split-bf16 GEMM ----------------
// C = A[M][K] @ BT[N][K]^T with A,B each split hi+lo:
//   C ~= Ahi*Bhi + Ahi*Blo + Alo*Bhi   (fp32 accumulate)
// Tile: BM=64 x BN_T x BK=64, 4 waves (2x2), each wave 32 x BN_T/2.
// EPI==0: hid = tanh(C + b1) split to hi/lo bf16.
// EPI==1: z = z + h*(C + b2); write z_cur(f32), z hi/lo, optional traj.
template<int EPI, int BN_T>
__global__ __launch_bounds__(256) void gemm_split(
    const u16* __restrict__ A_hi, const u16* __restrict__ A_lo,
    const u16* __restrict__ B_hi, const u16* __restrict__ B_lo,
    int K, int N,
    const float* __restrict__ bias,
    u16* __restrict__ hidhi_out, u16* __restrict__ hidlo_out,
    const float* z_in, float* z_out,
    u16* __restrict__ zhi_out, u16* __restrict__ zlo_out,
    float* __restrict__ traj,
    const float* __restrict__ tptr, int iv) {
    constexpr int BM = 64, BK = 64;
    constexpr int NI = BN_T / 32;        // 16-col fragments per wave in N
    constexpr int B_ISS = BN_T / 32;     // staging issues for one B tile
    __shared__ __align__(16) u16 lAh[BM * BK];
    __shared__ __align__(16) u16 lAl[BM * BK];
    __shared__ __align__(16) u16 lBh[BN_T * BK];
    __shared__ __align__(16) u16 lBl[BN_T * BK];

    const int tid = threadIdx.x;
    const int nTilesN = N / BN_T;
    const int tm = blockIdx.x / nTilesN;
    const int tn = blockIdx.x % nTilesN;
    const int m0 = tm * BM, n0 = tn * BN_T;
    const int wave = tid >> 6;
    const int lane = tid & 63;
    const int wr = wave >> 1, wc = wave & 1;   // 2x2 waves
    const int l15 = lane & 15;
    const int lgrp = lane >> 4;                // 0..3
    const int lk8 = lgrp * 8;

    f32x4 acc[2][NI];
    #pragma unroll
    for (int mi = 0; mi < 2; ++mi)
        #pragma unroll
        for (int ni = 0; ni < NI; ++ni)
            acc[mi][ni] = (f32x4){0.f, 0.f, 0.f, 0.f};

    // staging: linear LDS dest (wave-uniform base + lane*16), swizzled
    // GLOBAL source column:  cb = (L&127) ^ ((row&7)<<4)       [rule #21]
    const int niter = K / BK;
    for (int kt = 0; kt < niter; ++kt) {
        const int k0 = kt * BK;
        __syncthreads();   // previous tile fully consumed
        #pragma unroll
        for (int i = 0; i < 2; ++i) {
            const int L = (i * 256 + tid) * 16;        // byte offset in tile
            const int r = L >> 7;
            const int cb = (L & 127) ^ ((r & 7) << 4);
            const size_t goff = (size_t)(m0 + r) * K + k0 + (cb >> 1);
            const int ldsoff = (i * 256 + (tid & ~63)) * 8;  // elems, wave-uniform
            __builtin_amdgcn_global_load_lds(
                (const __attribute__((address_space(1))) void*)(A_hi + goff),
                (__attribute__((address_space(3))) void*)(&lAh[ldsoff]), 16, 0, 0);
            __builtin_amdgcn_global_load_lds(
                (const __attribute__((address_space(1))) void*)(A_lo + goff),
                (__attribute__((address_space(3))) void*)(&lAl[ldsoff]), 16, 0, 0);
        }
        #pragma unroll
        for (int i = 0; i < B_ISS; ++i) {
            const int L = (i * 256 + tid) * 16;
            const int r = L >> 7;
            const int cb = (L & 127) ^ ((r & 7) << 4);
            const size_t goff = (size_t)(n0 + r) * K + k0 + (cb >> 1);
            const int ldsoff = (i * 256 + (tid & ~63)) * 8;
            __builtin_amdgcn_global_load_lds(
                (const __attribute__((address_space(1))) void*)(B_hi + goff),
                (__attribute__((address_space(3))) void*)(&lBh[ldsoff]), 16, 0, 0);
            __builtin_amdgcn_global_load_lds(
                (const __attribute__((address_space(1))) void*)(B_lo + goff),
                (__attribute__((address_space(3))) void*)(&lBl[ldsoff]), 16, 0, 0);
        }
        __syncthreads();   // staging visible

        #pragma unroll
        for (int kk = 0; kk < BK; kk += 32) {
            bf16x8 afh[2], afl[2], bfh[NI], bfl[NI];
            #pragma unroll
            for (int mi = 0; mi < 2; ++mi) {
                const int row = wr * 32 + mi * 16 + l15;
                const int cbyte = ((kk + lk8) * 2) ^ ((row & 7) << 4);
                afh[mi] = *(const bf16x8*)((const char*)lAh + row * 128 + cbyte);
                afl[mi] = *(const bf16x8*)((const char*)lAl + row * 128 + cbyte);
            }
            #pragma unroll
            for (int ni = 0; ni < NI; ++ni) {
                const int row = wc * (BN_T / 2) + ni * 16 + l15;
                const int cbyte = ((kk + lk8) * 2) ^ ((row & 7) << 4);
                bfh[ni] = *(const bf16x8*)((const char*)lBh + row * 128 + cbyte);
                bfl[ni] = *(const bf16x8*)((const char*)lBl + row * 128 + cbyte);
            }
            #pragma unroll
            for (int mi = 0; mi < 2; ++mi)
                #pragma unroll
                for (int ni = 0; ni < NI; ++ni) {
                    acc[mi][ni] = __builtin_amdgcn_mfma_f32_16x16x32_bf16(
                        afh[mi], bfh[ni], acc[mi][ni], 0, 0, 0);
                    acc[mi][ni] = __builtin_amdgcn_mfma_f32_16x16x32_bf16(
                        afh[mi], bfl[ni], acc[mi][ni], 0, 0, 0);
                    acc[mi][ni] = __builtin_amdgcn_mfma_f32_16x16x32_bf16(
                        afl[mi], bfh[ni], acc[mi][ni], 0, 0, 0);
                }
        }
    }

    // ---- epilogue ----
    const int crow_base = m0 + wr * 32;
    const int ccol_base = n0 + wc * (BN_T / 2);
    if (EPI == 0) {
        #pragma unroll
        for (int mi = 0; mi < 2; ++mi)
            #pragma unroll
            for (int ni = 0; ni < NI; ++ni) {
                const int col = ccol_base + ni * 16 + l15;
                const float b = bias[col];
                #pragma unroll
                for (int r = 0; r < 4; ++r) {
                    const int row = crow_base + mi * 16 + lgrp * 4 + r;
                    const float v = tanhf(acc[mi][ni][r] + b);
                    const u16 hi = f2bf(v);
                    const size_t idx = (size_t)row * N + col;
                    hidhi_out[idx] = hi;
                    hidlo_out[idx] = f2bf(v - bf2f(hi));
                }
            }
    } else {
        const float hstep = fabsf(tptr[iv + 1] - tptr[iv]) * (1.0f / N_INNER);
        #pragma unroll
        for (int mi = 0; mi < 2; ++mi)
            #pragma unroll
            for (int ni = 0; ni < NI; ++ni) {
                const int col = ccol_base + ni * 16 + l15;
                const float b = bias[col];
                #pragma unroll
                for (int r = 0; r < 4; ++r) {
                    const int row = crow_base + mi * 16 + lgrp * 4 + r;
                    const size_t idx = (size_t)row * D + col;
                    const float v = z_in[idx] + hstep * (acc[mi][ni][r] + b);
                    z_out[idx] = v;
                    const u16 hi = f2bf(v);
                    zhi_out[idx] = hi;
                    zlo_out[idx] = f2bf(v - bf2f(hi));
                    if (traj) traj[idx] = v;
                }
            }
    }
}

// ---------------- host ----------------

extern "C" void kernel_launch(void* const* d_in, const int* in_sizes, int n_in,
                              void* d_out, int out_size, void* d_ws, size_t ws_size,
                              hipStream_t stream) {
    const float* z0 = (const float*)d_in[0];
    const float* t  = (const float*)d_in[1];
    const float* W1 = (const float*)d_in[2];
    const float* b1 = (const float*)d_in[3];
    const float* W2 = (const float*)d_in[4];
    const float* b2 = (const float*)d_in[5];
    float* out = (float*)d_out;

    char* ws = (char*)d_ws;
    u16*   W1T_hi = (u16*)(ws);                        // [H][D] bf16, 8 MB
    u16*   W1T_lo = (u16*)(ws + (8u << 20));
    u16*   W2T_hi = (u16*)(ws + (16u << 20));          // [D][H] bf16, 8 MB
    u16*   W2T_lo = (u16*)(ws + (24u << 20));
    float* z_cur  = (float*)(ws + (32u << 20));        // [BS][D] f32, 2 MB
    u16*   z_hi   = (u16*)(ws + (34u << 20));          // [BS][D] bf16, 1 MB
    u16*   z_lo   = (u16*)(ws + (35u << 20));
    u16*   hid_hi = (u16*)(ws + (36u << 20));          // [BS][H] bf16, 4 MB
    u16*   hid_lo = (u16*)(ws + (40u << 20));

    // prep
    transpose_split<<<dim3(H / 32, D / 32), 256, 0, stream>>>(W1, W1T_hi, W1T_lo, D, H);
    transpose_split<<<dim3(D / 32, H / 32), 256, 0, stream>>>(W2, W2T_hi, W2T_lo, H, D);
    init_z<<<(BS * D) / 256, 256, 0, stream>>>(z0, z_cur, z_hi, z_lo, out);

    const int g1 = (BS / 64) * (H / 64);   // 512 blocks (64x64 tiles)
    const int g2 = (BS / 64) * (D / 32);   // 256 blocks (64x32 tiles)

    for (int iv = 0; iv < T_STEPS - 1; ++iv) {
        for (int s = 0; s < N_INNER; ++s) {
            gemm_split<0, 64><<<g1, 256, 0, stream>>>(
                z_hi, z_lo, W1T_hi, W1T_lo, D, H, b1,
                hid_hi, hid_lo, nullptr, nullptr, nullptr, nullptr,
                nullptr, nullptr, 0);
            float* traj = (s == N_INNER - 1) ? out + (size_t)(iv + 1) * BS * D : nullptr;
            gemm_split<1, 32><<<g2, 256, 0, stream>>>(
                hid_hi, hid_lo, W2T_hi, W2T_lo, H, D, b2,
                nullptr, nullptr, z_cur, z_cur, z_hi, z_lo,
                traj, t, iv);
        }
    }
}

// Round 3
// 14474.236 us; speedup vs baseline: 1.2664x; 1.2664x over previous
//
#include <hip/hip_runtime.h>
#include <hip/hip_bf16.h>
#include <stdint.h>

#define BS 512
#define D 1024
#define H 4096
#define T_STEPS 64
#define N_INNER 4
#define SK 4

typedef __attribute__((ext_vector_type(8))) short bf16x8;
typedef __attribute__((ext_vector_type(4))) float f32x4;
typedef __attribute__((ext_vector_type(4))) unsigned short u16x4;
typedef unsigned short u16;

__device__ __forceinline__ u16 f2bf(float f) {
    unsigned int u = __float_as_uint(f);
    unsigned int r = (u + 0x7FFFu + ((u >> 16) & 1u)) >> 16;
    return (u16)r;
}
__device__ __forceinline__ float bf2f(u16 h) {
    return __uint_as_float(((unsigned int)h) << 16);
}

// ---------------- prep kernels ----------------

__global__ __launch_bounds__(256) void transpose_split(
    const float* __restrict__ src, u16* __restrict__ dst_hi,
    u16* __restrict__ dst_lo, int rows, int cols) {
    __shared__ float tile[32][33];
    const int bx = blockIdx.x;
    const int by = blockIdx.y;
    const int tx = threadIdx.x & 31;
    const int ty = threadIdx.x >> 5;
    const int c0 = bx * 32, r0 = by * 32;
    #pragma unroll
    for (int i = ty; i < 32; i += 8)
        tile[i][tx] = src[(size_t)(r0 + i) * cols + c0 + tx];
    __syncthreads();
    #pragma unroll
    for (int i = ty; i < 32; i += 8) {
        const float v = tile[tx][i];
        const u16 hi = f2bf(v);
        const u16 lo = f2bf(v - bf2f(hi));
        const size_t idx = (size_t)(c0 + i) * rows + r0 + tx;
        dst_hi[idx] = hi;
        dst_lo[idx] = lo;
    }
}

__global__ __launch_bounds__(256) void init_z(
    const float* __restrict__ z0, float* __restrict__ z_cur,
    u16* __restrict__ z_hi, u16* __restrict__ z_lo, float* __restrict__ out) {
    const int i = blockIdx.x * 256 + threadIdx.x;
    const float v = z0[i];
    z_cur[i] = v;
    const u16 hi = f2bf(v);
    z_hi[i] = hi;
    z_lo[i] = f2bf(v - bf2f(hi));
    out[i] = v;
}

// ---------------- staging helper ----------------
// 64x64 bf16 tile (hi+lo) -> linear LDS dest, inverse-swizzled global source
// (rule #21: dest linear, source column ^ ((row&7)<<4), read with same XOR).
__device__ __forceinline__ void stage64(
    const u16* __restrict__ src_hi, const u16* __restrict__ src_lo,
    u16* ldsh, u16* ldsl, int row0, int ldK, int k0, int tid) {
    #pragma unroll
    for (int i = 0; i < 2; ++i) {
        const int L = (i * 256 + tid) * 16;        // byte offset in tile
        const int r = L >> 7;
        const int cb = (L & 127) ^ ((r & 7) << 4);
        const size_t goff = (size_t)(row0 + r) * ldK + k0 + (cb >> 1);
        const int ldsoff = (i * 256 + (tid & ~63)) * 8;  // elems, wave-uniform
        __builtin_amdgcn_global_load_lds(
            (const __attribute__((address_space(1))) void*)(src_hi + goff),
            (__attribute__((address_space(3))) void*)(ldsh + ldsoff), 16, 0, 0);
        __builtin_amdgcn_global_load_lds(
            (const __attribute__((address_space(1))) void*)(src_lo + goff),
            (__attribute__((address_space(3))) void*)(ldsl + ldsoff), 16, 0, 0);
    }
}

// ---------------- fused split-bf16 GEMM (2-phase double-buffered) ----------------
// C = A @ BT^T, A,B split hi/lo: C ~= Ahi*Bhi + Ahi*Blo + Alo*Bhi.
// 64x64 tile, BK=64, 16 K-iterations, 4 waves (2x2) of 32x32.
// EPI==0: GEMM1. grid 512 = 8x64 tiles, K=1024, N=4096. hid=tanh(C+b1) hi/lo.
// EPI==1: GEMM2 split-K. grid 512 = SK(4) x 8x16 tiles, K-slice=1024.
//         writes fp32 partial (no bias).
template<int EPI>
__global__ __launch_bounds__(256, 2) void gemm_step(
    const u16* __restrict__ A_hi, const u16* __restrict__ A_lo,
    const u16* __restrict__ B_hi, const u16* __restrict__ B_lo,
    const float* __restrict__ bias,
    u16* __restrict__ hidhi_out, u16* __restrict__ hidlo_out,
    float* __restrict__ part) {
    __shared__ __align__(16) u16 lAh[2][4096];
    __shared__ __align__(16) u16 lAl[2][4096];
    __shared__ __align__(16) u16 lBh[2][4096];
    __shared__ __align__(16) u16 lBl[2][4096];

    const int tid = threadIdx.x;
    int tm, tn, sk, ldK;
    if (EPI == 0) {
        tm = blockIdx.x >> 6;  tn = blockIdx.x & 63;  sk = 0;    ldK = D;
    } else {
        sk = blockIdx.x >> 7;
        const int rem = blockIdx.x & 127;
        tm = rem >> 4;  tn = rem & 15;  ldK = H;
    }
    const int m0 = tm * 64, n0 = tn * 64;
    const int k0base = sk * 1024;

    const int wave = tid >> 6;
    const int lane = tid & 63;
    const int wr = wave >> 1, wc = wave & 1;
    const int l15 = lane & 15;
    const int lgrp = lane >> 4;
    const int lk8 = lgrp * 8;

    f32x4 acc[2][2];
    #pragma unroll
    for (int mi = 0; mi < 2; ++mi)
        #pragma unroll
        for (int ni = 0; ni < 2; ++ni)
            acc[mi][ni] = (f32x4){0.f, 0.f, 0.f, 0.f};

    // prologue: stage tile 0
    stage64(A_hi, A_lo, lAh[0], lAl[0], m0, ldK, k0base, tid);
    stage64(B_hi, B_lo, lBh[0], lBl[0], n0, ldK, k0base, tid);
    __syncthreads();

    int cur = 0;
    for (int kt = 0; kt < 16; ++kt) {
        // issue next-tile stage FIRST (latency hides under compute below)
        if (kt < 15) {
            const int k0 = k0base + (kt + 1) * 64;
            stage64(A_hi, A_lo, lAh[cur ^ 1], lAl[cur ^ 1], m0, ldK, k0, tid);
            stage64(B_hi, B_lo, lBh[cur ^ 1], lBl[cur ^ 1], n0, ldK, k0, tid);
        }
        const char* Ah = (const char*)lAh[cur];
        const char* Al = (const char*)lAl[cur];
        const char* Bh = (const char*)lBh[cur];
        const char* Bl = (const char*)lBl[cur];
        #pragma unroll
        for (int kk = 0; kk < 64; kk += 32) {
            bf16x8 afh[2], afl[2], bfh[2], bfl[2];
            #pragma unroll
            for (int mi = 0; mi < 2; ++mi) {
                const int row = wr * 32 + mi * 16 + l15;
                const int cbyte = ((kk + lk8) * 2) ^ ((row & 7) << 4);
                afh[mi] = *(const bf16x8*)(Ah + row * 128 + cbyte);
                afl[mi] = *(const bf16x8*)(Al + row * 128 + cbyte);
            }
            #pragma unroll
            for (int ni = 0; ni < 2; ++ni) {
                const int row = wc * 32 + ni * 16 + l15;
                const int cbyte = ((kk + lk8) * 2) ^ ((row & 7) << 4);
                bfh[ni] = *(const bf16x8*)(Bh + row * 128 + cbyte);
                bfl[ni] = *(const bf16x8*)(Bl + row * 128 + cbyte);
            }
            #pragma unroll
            for (int mi = 0; mi < 2; ++mi)
                #pragma unroll
                for (int ni = 0; ni < 2; ++ni) {
                    acc[mi][ni] = __builtin_amdgcn_mfma_f32_16x16x32_bf16(
                        afh[mi], bfh[ni], acc[mi][ni], 0, 0, 0);
                    acc[mi][ni] = __builtin_amdgcn_mfma_f32_16x16x32_bf16(
                        afh[mi], bfl[ni], acc[mi][ni], 0, 0, 0);
                    acc[mi][ni] = __builtin_amdgcn_mfma_f32_16x16x32_bf16(
                        afl[mi], bfh[ni], acc[mi][ni], 0, 0, 0);
                }
        }
        __syncthreads();   // drains vmcnt: next tile staged + cur fully consumed
        cur ^= 1;
    }

    // ---- epilogue ----
    const int crow_base = m0 + wr * 32;
    const int ccol_base = n0 + wc * 32;
    if (EPI == 0) {
        #pragma unroll
        for (int mi = 0; mi < 2; ++mi)
            #pragma unroll
            for (int ni = 0; ni < 2; ++ni) {
                const int col = ccol_base + ni * 16 + l15;
                const float b = bias[col];
                #pragma unroll
                for (int r = 0; r < 4; ++r) {
                    const int row = crow_base + mi * 16 + lgrp * 4 + r;
                    const float v = tanhf(acc[mi][ni][r] + b);
                    const u16 hi = f2bf(v);
                    const size_t idx = (size_t)row * H + col;
                    hidhi_out[idx] = hi;
                    hidlo_out[idx] = f2bf(v - bf2f(hi));
                }
            }
    } else {
        float* p = part + (size_t)sk * BS * D;
        #pragma unroll
        for (int mi = 0; mi < 2; ++mi)
            #pragma unroll
            for (int ni = 0; ni < 2; ++ni) {
                const int col = ccol_base + ni * 16 + l15;
                #pragma unroll
                for (int r = 0; r < 4; ++r) {
                    const int row = crow_base + mi * 16 + lgrp * 4 + r;
                    p[(size_t)row * D + col] = acc[mi][ni][r];
                }
            }
    }
}

// ---------------- split-K reduce + Euler update ----------------
__global__ __launch_bounds__(256) void reduce_update(
    const float* __restrict__ part, const float* __restrict__ b2,
    const float* __restrict__ z_in, float* __restrict__ z_out,
    u16* __restrict__ zhi, u16* __restrict__ zlo,
    float* __restrict__ traj, const float* __restrict__ tptr, int iv) {
    const int i = (blockIdx.x * 256 + threadIdx.x) * 4;
    const size_t SZ = (size_t)BS * D;
    const float4 p0 = *(const float4*)(part + i);
    const float4 p1 = *(const float4*)(part + SZ + i);
    const float4 p2 = *(const float4*)(part + 2 * SZ + i);
    const float4 p3 = *(const float4*)(part + 3 * SZ + i);
    const float4 b  = *(const float4*)(b2 + (i & (D - 1)));
    const float4 z  = *(const float4*)(z_in + i);
    const float h = fabsf(tptr[iv + 1] - tptr[iv]) * (1.0f / N_INNER);
    float4 v;
    v.x = z.x + h * (p0.x + p1.x + p2.x + p3.x + b.x);
    v.y = z.y + h * (p0.y + p1.y + p2.y + p3.y + b.y);
    v.z = z.z + h * (p0.z + p1.z + p2.z + p3.z + b.z);
    v.w = z.w + h * (p0.w + p1.w + p2.w + p3.w + b.w);
    *(float4*)(z_out + i) = v;
    u16x4 hi4, lo4;
    hi4.x = f2bf(v.x); lo4.x = f2bf(v.x - bf2f(hi4.x));
    hi4.y = f2bf(v.y); lo4.y = f2bf(v.y - bf2f(hi4.y));
    hi4.z = f2bf(v.z); lo4.z = f2bf(v.z - bf2f(hi4.z));
    hi4.w = f2bf(v.w); lo4.w = f2bf(v.w - bf2f(hi4.w));
    *(u16x4*)(zhi + i) = hi4;
    *(u16x4*)(zlo + i) = lo4;
    if (traj) *(float4*)(traj + i) = v;
}

// ---------------- host ----------------

extern "C" void kernel_launch(void* const* d_in, const int* in_sizes, int n_in,
                              void* d_out, int out_size, void* d_ws, size_t ws_size,
                              hipStream_t stream) {
    const float* z0 = (const float*)d_in[0];
    const float* t  = (const float*)d_in[1];
    const float* W1 = (const float*)d_in[2];
    const float* b1 = (const float*)d_in[3];
    const float* W2 = (const float*)d_in[4];
    const float* b2 = (const float*)d_in[5];
    float* out = (float*)d_out;

    char* ws = (char*)d_ws;
    u16*   W1T_hi = (u16*)(ws);                        // [H][D] 8 MB
    u16*   W1T_lo = (u16*)(ws + (8u << 20));
    u16*   W2T_hi = (u16*)(ws + (16u << 20));          // [D][H] 8 MB
    u16*   W2T_lo = (u16*)(ws + (24u << 20));
    float* z_cur  = (float*)(ws + (32u << 20));        // [BS][D] f32
    u16*   z_hi   = (u16*)(ws + (34u << 20));
    u16*   z_lo   = (u16*)(ws + (35u << 20));
    u16*   hid_hi = (u16*)(ws + (36u << 20));          // [BS][H]
    u16*   hid_lo = (u16*)(ws + (40u << 20));
    float* part   = (float*)(ws + (44u << 20));        // SK x [BS][D] f32, 8 MB

    transpose_split<<<dim3(H / 32, D / 32), 256, 0, stream>>>(W1, W1T_hi, W1T_lo, D, H);
    transpose_split<<<dim3(D / 32, H / 32), 256, 0, stream>>>(W2, W2T_hi, W2T_lo, H, D);
    init_z<<<(BS * D) / 256, 256, 0, stream>>>(z0, z_cur, z_hi, z_lo, out);

    for (int iv = 0; iv < T_STEPS - 1; ++iv) {
        for (int s = 0; s < N_INNER; ++s) {
            gemm_step<0><<<512, 256, 0, stream>>>(
                z_hi, z_lo, W1T_hi, W1T_lo, b1, hid_hi, hid_lo, nullptr);
            gemm_step<1><<<512, 256, 0, stream>>>(
                hid_hi, hid_lo, W2T_hi, W2T_lo, nullptr, nullptr, nullptr, part);
            float* traj = (s == N_INNER - 1) ? out + (size_t)(iv + 1) * BS * D : nullptr;
            reduce_update<<<512, 256, 0, stream>>>(
                part, b2, z_cur, z_cur, z_hi, z_lo, traj, t, iv);
        }
    }
}

// Round 4
// 9927.219 us; speedup vs baseline: 1.8465x; 1.4580x over previous
//
#include <hip/hip_runtime.h>
#include <hip/hip_bf16.h>
#include <stdint.h>

#define BS 512
#define D 1024
#define H 4096
#define T_STEPS 64
#define N_INNER 4
#define SK 4

typedef __attribute__((ext_vector_type(8))) _Float16 f16x8;
typedef __attribute__((ext_vector_type(4))) float f32x4;
typedef __attribute__((ext_vector_type(4))) unsigned short u16x4;
typedef unsigned short u16;

__device__ __forceinline__ u16 f2h_bits(float f) {
    _Float16 h = (_Float16)f;
    return __builtin_bit_cast(u16, h);
}
__device__ __forceinline__ float h2f(u16 b) {
    return (float)__builtin_bit_cast(_Float16, b);
}
__device__ __forceinline__ float fast_tanh(float x) {
    // tanh(x) = 1 - 2/(e^{2x}+1); exp overflow -> +1, underflow -> -1 (correct)
    float e = __expf(2.0f * x);
    return 1.0f - 2.0f / (e + 1.0f);
}

// ---------------- prep kernels ----------------

// src [rows][cols] f32 -> dst_hi/dst_lo [cols][rows] fp16 (hi + residual lo)
__global__ __launch_bounds__(256) void transpose_split(
    const float* __restrict__ src, u16* __restrict__ dst_hi,
    u16* __restrict__ dst_lo, int rows, int cols) {
    __shared__ float tile[32][33];
    const int bx = blockIdx.x;
    const int by = blockIdx.y;
    const int tx = threadIdx.x & 31;
    const int ty = threadIdx.x >> 5;
    const int c0 = bx * 32, r0 = by * 32;
    #pragma unroll
    for (int i = ty; i < 32; i += 8)
        tile[i][tx] = src[(size_t)(r0 + i) * cols + c0 + tx];
    __syncthreads();
    #pragma unroll
    for (int i = ty; i < 32; i += 8) {
        const float v = tile[tx][i];
        const u16 hi = f2h_bits(v);
        const u16 lo = f2h_bits(v - h2f(hi));
        const size_t idx = (size_t)(c0 + i) * rows + r0 + tx;
        dst_hi[idx] = hi;
        dst_lo[idx] = lo;
    }
}

__global__ __launch_bounds__(256) void init_z(
    const float* __restrict__ z0, float* __restrict__ z_cur,
    u16* __restrict__ z_h, float* __restrict__ out) {
    const int i = blockIdx.x * 256 + threadIdx.x;
    const float v = z0[i];
    z_cur[i] = v;
    z_h[i] = f2h_bits(v);
    out[i] = v;
}

// ---------------- staging helper ----------------
// 64x64 fp16 tile -> linear LDS dest, inverse-swizzled global source
// (rule #21: dest linear, source column ^ ((row&7)<<4), read with same XOR).
__device__ __forceinline__ void stage_one(
    const u16* __restrict__ src, u16* lds, int row0, int ldK, int k0, int tid) {
    #pragma unroll
    for (int i = 0; i < 2; ++i) {
        const int L = (i * 256 + tid) * 16;        // byte offset in tile
        const int r = L >> 7;
        const int cb = (L & 127) ^ ((r & 7) << 4);
        const size_t goff = (size_t)(row0 + r) * ldK + k0 + (cb >> 1);
        const int ldsoff = (i * 256 + (tid & ~63)) * 8;  // elems, wave-uniform
        __builtin_amdgcn_global_load_lds(
            (const __attribute__((address_space(1))) void*)(src + goff),
            (__attribute__((address_space(3))) void*)(lds + ldsoff), 16, 0, 0);
    }
}

// ---------------- fused fp16 GEMM (2-term, double-buffered) ----------------
// C = A[M][K] @ BT[N][K]^T ; A single fp16, B split hi/lo:
//   C ~= A*Bhi + A*Blo   (fp32 accumulate)
// 64x64 tile, BK=64, 16 K-iterations, 4 waves (2x2) of 32x32.
// EPI==0: GEMM1. grid 512 = 8x64 tiles, K=1024, N=4096. hid=tanh(C+b1) fp16.
// EPI==1: GEMM2 split-K. grid 512 = SK(4) x 8x16 tiles, K-slice=1024.
//         writes fp32 partial (no bias).
template<int EPI>
__global__ __launch_bounds__(256, 2) void gemm_step(
    const u16* __restrict__ A_h,
    const u16* __restrict__ B_hi, const u16* __restrict__ B_lo,
    const float* __restrict__ bias,
    u16* __restrict__ hid_out,
    float* __restrict__ part) {
    __shared__ __align__(16) u16 lA[2][4096];
    __shared__ __align__(16) u16 lBh[2][4096];
    __shared__ __align__(16) u16 lBl[2][4096];

    const int tid = threadIdx.x;
    int tm, tn, sk, ldK;
    if (EPI == 0) {
        tm = blockIdx.x >> 6;  tn = blockIdx.x & 63;  sk = 0;  ldK = D;
    } else {
        sk = blockIdx.x >> 7;
        const int rem = blockIdx.x & 127;
        tm = rem >> 4;  tn = rem & 15;  ldK = H;
    }
    const int m0 = tm * 64, n0 = tn * 64;
    const int k0base = sk * 1024;

    const int wave = tid >> 6;
    const int lane = tid & 63;
    const int wr = wave >> 1, wc = wave & 1;
    const int l15 = lane & 15;
    const int lgrp = lane >> 4;
    const int lk8 = lgrp * 8;

    f32x4 acc[2][2];
    #pragma unroll
    for (int mi = 0; mi < 2; ++mi)
        #pragma unroll
        for (int ni = 0; ni < 2; ++ni)
            acc[mi][ni] = (f32x4){0.f, 0.f, 0.f, 0.f};

    // prologue: stage tile 0
    stage_one(A_h,  lA[0],  m0, ldK, k0base, tid);
    stage_one(B_hi, lBh[0], n0, ldK, k0base, tid);
    stage_one(B_lo, lBl[0], n0, ldK, k0base, tid);
    __syncthreads();

    int cur = 0;
    for (int kt = 0; kt < 16; ++kt) {
        // issue next-tile stage FIRST (latency hides under compute below)
        if (kt < 15) {
            const int k0 = k0base + (kt + 1) * 64;
            stage_one(A_h,  lA[cur ^ 1],  m0, ldK, k0, tid);
            stage_one(B_hi, lBh[cur ^ 1], n0, ldK, k0, tid);
            stage_one(B_lo, lBl[cur ^ 1], n0, ldK, k0, tid);
        }
        const char* Ah = (const char*)lA[cur];
        const char* Bh = (const char*)lBh[cur];
        const char* Bl = (const char*)lBl[cur];
        #pragma unroll
        for (int kk = 0; kk < 64; kk += 32) {
            f16x8 af[2], bfh[2], bfl[2];
            #pragma unroll
            for (int mi = 0; mi < 2; ++mi) {
                const int row = wr * 32 + mi * 16 + l15;
                const int cbyte = ((kk + lk8) * 2) ^ ((row & 7) << 4);
                af[mi] = *(const f16x8*)(Ah + row * 128 + cbyte);
            }
            #pragma unroll
            for (int ni = 0; ni < 2; ++ni) {
                const int row = wc * 32 + ni * 16 + l15;
                const int cbyte = ((kk + lk8) * 2) ^ ((row & 7) << 4);
                bfh[ni] = *(const f16x8*)(Bh + row * 128 + cbyte);
                bfl[ni] = *(const f16x8*)(Bl + row * 128 + cbyte);
            }
            #pragma unroll
            for (int mi = 0; mi < 2; ++mi)
                #pragma unroll
                for (int ni = 0; ni < 2; ++ni) {
                    acc[mi][ni] = __builtin_amdgcn_mfma_f32_16x16x32_f16(
                        af[mi], bfh[ni], acc[mi][ni], 0, 0, 0);
                    acc[mi][ni] = __builtin_amdgcn_mfma_f32_16x16x32_f16(
                        af[mi], bfl[ni], acc[mi][ni], 0, 0, 0);
                }
        }
        __syncthreads();   // drains vmcnt: next tile staged + cur fully consumed
        cur ^= 1;
    }

    // ---- epilogue ----
    const int crow_base = m0 + wr * 32;
    const int ccol_base = n0 + wc * 32;
    if (EPI == 0) {
        #pragma unroll
        for (int mi = 0; mi < 2; ++mi)
            #pragma unroll
            for (int ni = 0; ni < 2; ++ni) {
                const int col = ccol_base + ni * 16 + l15;
                const float b = bias[col];
                #pragma unroll
                for (int r = 0; r < 4; ++r) {
                    const int row = crow_base + mi * 16 + lgrp * 4 + r;
                    const float v = fast_tanh(acc[mi][ni][r] + b);
                    hid_out[(size_t)row * H + col] = f2h_bits(v);
                }
            }
    } else {
        float* p = part + (size_t)sk * BS * D;
        #pragma unroll
        for (int mi = 0; mi < 2; ++mi)
            #pragma unroll
            for (int ni = 0; ni < 2; ++ni) {
                const int col = ccol_base + ni * 16 + l15;
                #pragma unroll
                for (int r = 0; r < 4; ++r) {
                    const int row = crow_base + mi * 16 + lgrp * 4 + r;
                    p[(size_t)row * D + col] = acc[mi][ni][r];
                }
            }
    }
}

// ---------------- split-K reduce + Euler update ----------------
__global__ __launch_bounds__(256) void reduce_update(
    const float* __restrict__ part, const float* __restrict__ b2,
    const float* __restrict__ z_in, float* __restrict__ z_out,
    u16* __restrict__ zh,
    float* __restrict__ traj, const float* __restrict__ tptr, int iv) {
    const int i = (blockIdx.x * 256 + threadIdx.x) * 4;
    const size_t SZ = (size_t)BS * D;
    const float4 p0 = *(const float4*)(part + i);
    const float4 p1 = *(const float4*)(part + SZ + i);
    const float4 p2 = *(const float4*)(part + 2 * SZ + i);
    const float4 p3 = *(const float4*)(part + 3 * SZ + i);
    const float4 b  = *(const float4*)(b2 + (i & (D - 1)));
    const float4 z  = *(const float4*)(z_in + i);
    const float h = fabsf(tptr[iv + 1] - tptr[iv]) * (1.0f / N_INNER);
    float4 v;
    v.x = z.x + h * (p0.x + p1.x + p2.x + p3.x + b.x);
    v.y = z.y + h * (p0.y + p1.y + p2.y + p3.y + b.y);
    v.z = z.z + h * (p0.z + p1.z + p2.z + p3.z + b.z);
    v.w = z.w + h * (p0.w + p1.w + p2.w + p3.w + b.w);
    *(float4*)(z_out + i) = v;
    u16x4 h4;
    h4.x = f2h_bits(v.x);
    h4.y = f2h_bits(v.y);
    h4.z = f2h_bits(v.z);
    h4.w = f2h_bits(v.w);
    *(u16x4*)(zh + i) = h4;
    if (traj) *(float4*)(traj + i) = v;
}

// ---------------- host ----------------

extern "C" void kernel_launch(void* const* d_in, const int* in_sizes, int n_in,
                              void* d_out, int out_size, void* d_ws, size_t ws_size,
                              hipStream_t stream) {
    const float* z0 = (const float*)d_in[0];
    const float* t  = (const float*)d_in[1];
    const float* W1 = (const float*)d_in[2];
    const float* b1 = (const float*)d_in[3];
    const float* W2 = (const float*)d_in[4];
    const float* b2 = (const float*)d_in[5];
    float* out = (float*)d_out;

    char* ws = (char*)d_ws;
    u16*   W1T_hi = (u16*)(ws);                        // [H][D] fp16, 8 MB
    u16*   W1T_lo = (u16*)(ws + (8u << 20));
    u16*   W2T_hi = (u16*)(ws + (16u << 20));          // [D][H] fp16, 8 MB
    u16*   W2T_lo = (u16*)(ws + (24u << 20));
    float* z_cur  = (float*)(ws + (32u << 20));        // [BS][D] f32
    u16*   z_h    = (u16*)(ws + (34u << 20));          // [BS][D] fp16
    u16*   hid_h  = (u16*)(ws + (36u << 20));          // [BS][H] fp16
    float* part   = (float*)(ws + (44u << 20));        // SK x [BS][D] f32, 8 MB

    transpose_split<<<dim3(H / 32, D / 32), 256, 0, stream>>>(W1, W1T_hi, W1T_lo, D, H);
    transpose_split<<<dim3(D / 32, H / 32), 256, 0, stream>>>(W2, W2T_hi, W2T_lo, H, D);
    init_z<<<(BS * D) / 256, 256, 0, stream>>>(z0, z_cur, z_h, out);

    for (int iv = 0; iv < T_STEPS - 1; ++iv) {
        for (int s = 0; s < N_INNER; ++s) {
            gemm_step<0><<<512, 256, 0, stream>>>(
                z_h, W1T_hi, W1T_lo, b1, hid_h, nullptr);
            gemm_step<1><<<512, 256, 0, stream>>>(
                hid_h, W2T_hi, W2T_lo, nullptr, nullptr, part);
            float* traj = (s == N_INNER - 1) ? out + (size_t)(iv + 1) * BS * D : nullptr;
            reduce_update<<<512, 256, 0, stream>>>(
                part, b2, z_cur, z_cur, z_h, traj, t, iv);
        }
    }
}